// Round 2
// baseline (1083.402 us; speedup 1.0000x reference)
//
#include <hip/hip_runtime.h>
#include <math.h>

#define NUM_K 19
#define CDIM 512
#define NPLANES 38    // planes 0..18: features_s, 19..37: features_t

typedef __attribute__((address_space(3))) float lds_float_t;

// Non-returning LDS float add: single ds_add_f32, no dependency chain, no CAS.
__device__ __forceinline__ void lds_fadd(unsigned addr, float v) {
    asm volatile("ds_add_f32 %0, %1" :: "v"(addr), "v"(v) : "memory");
}

// ---------------------------------------------------------------------------
// Kernel 1: per-class channel sums.
// One wave per (b,c) row (4096 rows), 4 waves per 256-thread block.
// LDS accumulator plane layout acc[class_plane][tid]: bank = tid&31 regardless
// of label -> every ds_add_f32 is exactly 2-way aliased (free, m136).
// Each thread owns its own column -> no cross-thread races, no barrier.
// mode=1: write contention-free per-(k,b,c) partials. mode=0: float atomicAdd
// fallback (only if workspace is tiny).
// ---------------------------------------------------------------------------
__global__ __launch_bounds__(256)
void class_sum_kernel(const float* __restrict__ fs, const float* __restrict__ ft,
                      const int* __restrict__ lab,
                      float* __restrict__ outS, float* __restrict__ outT,
                      const int mode) {
    __shared__ float acc[NPLANES][256];
    const int tid = threadIdx.x;
#pragma unroll
    for (int k = 0; k < NPLANES; ++k) acc[k][tid] = 0.0f;

    // LDS byte offset of this thread's column base: &acc[0][tid]
    const unsigned lds_base =
        (unsigned)(unsigned long long)(lds_float_t*)(&acc[0][tid]);

    const int wv = tid >> 6;
    const int lane = tid & 63;
    const int row = (blockIdx.x << 2) + wv;      // 0..4095 == b*512 + c
    const int b = row >> 9;
    const int c = row & 511;

    const float* ps = fs + ((size_t)row << 14);  // row * 16384
    const float* pt = ft + ((size_t)row << 14);
    const int*   pl = lab + ((size_t)b << 14);

    for (int it = 0; it < 64; it += 2) {
        const int i0 = (it << 8) + (lane << 2);  // float4 coalesced
        const int i1 = i0 + 256;
        const float4 vs0 = *(const float4*)(ps + i0);
        const float4 vt0 = *(const float4*)(pt + i0);
        const int4   l0  = *(const int4*)(pl + i0);
        const float4 vs1 = *(const float4*)(ps + i1);
        const float4 vt1 = *(const float4*)(pt + i1);
        const int4   l1  = *(const int4*)(pl + i1);

        lds_fadd(lds_base + ((unsigned)l0.x << 10), vs0.x);
        lds_fadd(lds_base + ((unsigned)l0.y << 10), vs0.y);
        lds_fadd(lds_base + ((unsigned)l0.z << 10), vs0.z);
        lds_fadd(lds_base + ((unsigned)l0.w << 10), vs0.w);
        lds_fadd(lds_base + ((unsigned)(l0.x + NUM_K) << 10), vt0.x);
        lds_fadd(lds_base + ((unsigned)(l0.y + NUM_K) << 10), vt0.y);
        lds_fadd(lds_base + ((unsigned)(l0.z + NUM_K) << 10), vt0.z);
        lds_fadd(lds_base + ((unsigned)(l0.w + NUM_K) << 10), vt0.w);

        lds_fadd(lds_base + ((unsigned)l1.x << 10), vs1.x);
        lds_fadd(lds_base + ((unsigned)l1.y << 10), vs1.y);
        lds_fadd(lds_base + ((unsigned)l1.z << 10), vs1.z);
        lds_fadd(lds_base + ((unsigned)l1.w << 10), vs1.w);
        lds_fadd(lds_base + ((unsigned)(l1.x + NUM_K) << 10), vt1.x);
        lds_fadd(lds_base + ((unsigned)(l1.y + NUM_K) << 10), vt1.y);
        lds_fadd(lds_base + ((unsigned)(l1.z + NUM_K) << 10), vt1.z);
        lds_fadd(lds_base + ((unsigned)(l1.w + NUM_K) << 10), vt1.w);
    }

    // Drain outstanding ds_adds before reading our column back.
    asm volatile("s_waitcnt lgkmcnt(0)" ::: "memory");

    for (int k = 0; k < NUM_K; ++k) {
        float v = acc[k][tid];
        float w = acc[NUM_K + k][tid];
#pragma unroll
        for (int off = 32; off > 0; off >>= 1) {
            v += __shfl_down(v, off, 64);
            w += __shfl_down(w, off, 64);
        }
        if (lane == 0) {
            if (mode) {  // contention-free partials [k][b][c]
                outS[(k * 8 + b) * CDIM + c] = v;
                outT[(k * 8 + b) * CDIM + c] = w;
            } else {
                atomicAdd(&outS[k * CDIM + c], v);
                atomicAdd(&outT[k * CDIM + c], w);
            }
        }
    }
}

// ---------------------------------------------------------------------------
// Kernel 2: per-class pixel counts (int atomics = native, no CAS).
// ---------------------------------------------------------------------------
__global__ __launch_bounds__(256)
void count_kernel(const int* __restrict__ lab, int* __restrict__ counts) {
    __shared__ int h[NUM_K];
    const int tid = threadIdx.x;
    if (tid < NUM_K) h[tid] = 0;
    __syncthreads();
    const int i = blockIdx.x * 256 + tid;      // one int4 per thread
    const int4 l4 = ((const int4*)lab)[i];
    atomicAdd(&h[l4.x], 1);
    atomicAdd(&h[l4.y], 1);
    atomicAdd(&h[l4.z], 1);
    atomicAdd(&h[l4.w], 1);
    __syncthreads();
    if (tid < NUM_K) atomicAdd(&counts[tid], h[tid]);
}

// ---------------------------------------------------------------------------
// Kernel 3: reduce partials, normalize, 19x19 logits, masked LSE loss.
// ---------------------------------------------------------------------------
__global__ __launch_bounds__(1024)
void finalize_kernel(const float* __restrict__ Ss, const float* __restrict__ St,
                     const int* __restrict__ counts, float* __restrict__ out,
                     const int mode) {
    __shared__ float ms[NUM_K][CDIM];
    __shared__ float mt[NUM_K][CDIM];
    __shared__ float scs[NUM_K], sct[NUM_K], cnt[NUM_K], invd[NUM_K];
    __shared__ float logits[NUM_K][NUM_K];
    const int tid = threadIdx.x;
    if (tid < NUM_K) {
        const float cv = (float)counts[tid];
        cnt[tid] = cv;
        invd[tid] = 1.0f / fmaxf(cv, 1.0f);
    }
    __syncthreads();

    float* msf = &ms[0][0];
    float* mtf = &mt[0][0];
    for (int i = tid; i < NUM_K * CDIM; i += 1024) {
        const int k = i >> 9, c = i & 511;
        float ssum, tsum;
        if (mode) {
            ssum = 0.0f; tsum = 0.0f;
            const float* pps = Ss + (size_t)(k * 8) * CDIM + c;
            const float* ppt = St + (size_t)(k * 8) * CDIM + c;
#pragma unroll
            for (int bb = 0; bb < 8; ++bb) {
                ssum += pps[bb * CDIM];
                tsum += ppt[bb * CDIM];
            }
        } else {
            ssum = Ss[i]; tsum = St[i];
        }
        const float id = invd[k];
        msf[i] = ssum * id;
        mtf[i] = tsum * id;
    }
    __syncthreads();

    const int wv = tid >> 6, lane = tid & 63;
    // Row L2 norms -> scale factors (normalization folded into logits).
    for (int k = wv; k < NUM_K; k += 16) {
        const float4* rs = (const float4*)&ms[k][0];
        const float4* rt = (const float4*)&mt[k][0];
        const float4 a0 = rs[lane * 2], a1 = rs[lane * 2 + 1];
        const float4 b0 = rt[lane * 2], b1 = rt[lane * 2 + 1];
        float ssum = a0.x*a0.x + a0.y*a0.y + a0.z*a0.z + a0.w*a0.w
                   + a1.x*a1.x + a1.y*a1.y + a1.z*a1.z + a1.w*a1.w;
        float tsum = b0.x*b0.x + b0.y*b0.y + b0.z*b0.z + b0.w*b0.w
                   + b1.x*b1.x + b1.y*b1.y + b1.z*b1.z + b1.w*b1.w;
#pragma unroll
        for (int off = 32; off > 0; off >>= 1) {
            ssum += __shfl_down(ssum, off, 64);
            tsum += __shfl_down(tsum, off, 64);
        }
        if (lane == 0) {
            scs[k] = 1.0f / fmaxf(sqrtf(ssum), 1e-12f);
            sct[k] = 1.0f / fmaxf(sqrtf(tsum), 1e-12f);
        }
    }
    __syncthreads();

    // logits[i][j] = (norm_s[i] . norm_t[j]) / TEMP
    for (int i = wv; i < NUM_K; i += 16) {
        const float4* rs = (const float4*)&ms[i][0];
        const float4 a0 = rs[lane * 2], a1 = rs[lane * 2 + 1];
        for (int j = 0; j < NUM_K; ++j) {
            const float4* rt = (const float4*)&mt[j][0];
            const float4 b0 = rt[lane * 2], b1 = rt[lane * 2 + 1];
            float d = a0.x*b0.x + a0.y*b0.y + a0.z*b0.z + a0.w*b0.w
                    + a1.x*b1.x + a1.y*b1.y + a1.z*b1.z + a1.w*b1.w;
#pragma unroll
            for (int off = 32; off > 0; off >>= 1) d += __shfl_down(d, off, 64);
            if (lane == 0) logits[i][j] = d * scs[i] * sct[j] * 10.0f;
        }
    }
    __syncthreads();

    if (wv == 0) {
        float val = 0.0f, pres = 0.0f;
        if (lane < NUM_K) {
            float m = -3.0e38f;
            for (int j = 0; j < NUM_K; ++j) m = fmaxf(m, logits[lane][j]);
            float s = 0.0f;
            for (int j = 0; j < NUM_K; ++j) s += expf(logits[lane][j] - m);
            const float lse = m + logf(s);
            if (cnt[lane] > 0.0f) { val = logits[lane][lane] - lse; pres = 1.0f; }
        }
#pragma unroll
        for (int off = 32; off > 0; off >>= 1) {
            val += __shfl_down(val, off, 64);
            pres += __shfl_down(pres, off, 64);
        }
        if (lane == 0) out[0] = -val / pres;
    }
}

extern "C" void kernel_launch(void* const* d_in, const int* in_sizes, int n_in,
                              void* d_out, int out_size, void* d_ws, size_t ws_size,
                              hipStream_t stream) {
    const float* fs = (const float*)d_in[0];
    const float* ft = (const float*)d_in[1];
    const int* lab = (const int*)d_in[2];

    // Workspace layout: [counts: 32 ints][Ss][St]
    int* counts = (int*)d_ws;
    float* Ss = (float*)((char*)d_ws + 128);

    const size_t partial_elems = (size_t)NUM_K * 8 * CDIM;   // 77824 per tensor
    const size_t small_elems = (size_t)NUM_K * CDIM;         // 9728 per tensor
    const int mode = (ws_size >= 128 + 2 * partial_elems * sizeof(float)) ? 1 : 0;
    const size_t elems = mode ? partial_elems : small_elems;
    float* St = Ss + elems;

    // Zero counts always; zero sum buffers only in atomic fallback mode.
    const size_t zbytes = mode ? 128 : (128 + 2 * small_elems * sizeof(float));
    hipMemsetAsync(d_ws, 0, zbytes, stream);

    hipLaunchKernelGGL(count_kernel, dim3(131072 / 4 / 256), dim3(256), 0, stream,
                       lab, counts);
    hipLaunchKernelGGL(class_sum_kernel, dim3(4096 / 4), dim3(256), 0, stream,
                       fs, ft, lab, Ss, St, mode);
    hipLaunchKernelGGL(finalize_kernel, dim3(1), dim3(1024), 0, stream,
                       Ss, St, counts, (float*)d_out, mode);
}

// Round 3
// 559.086 us; speedup vs baseline: 1.9378x; 1.9378x over previous
//
#include <hip/hip_runtime.h>
#include <math.h>

#define NUM_K 19
#define CDIM 512
#define NPLANES 38    // planes 0..18: features_s, 19..37: features_t

// ---------------------------------------------------------------------------
// Kernel 1: per-class channel sums.
// One wave per (b,c) row (4096 rows), 4 waves per 256-thread block.
// LDS accumulator plane layout acc[class_plane][tid]: bank = tid&31 regardless
// of label -> every DS access is exactly 2-way aliased (free, m136).
// Each thread owns its own column -> plain non-atomic read+add+write is
// race-free. NO LDS ATOMICS: the LDS atomic unit runs ~200 cyc/wave64 op
// (measured R1/R2 both pinned at 685 us); plain ds_read/ds_write run ~6 cyc.
// ---------------------------------------------------------------------------
__global__ __launch_bounds__(256)
void class_sum_kernel(const float* __restrict__ fs, const float* __restrict__ ft,
                      const int* __restrict__ lab,
                      float* __restrict__ outS, float* __restrict__ outT,
                      const int mode) {
    __shared__ float acc[NPLANES][256];
    const int tid = threadIdx.x;
#pragma unroll
    for (int k = 0; k < NPLANES; ++k) acc[k][tid] = 0.0f;

    const int wv = tid >> 6;
    const int lane = tid & 63;
    const int row = (blockIdx.x << 2) + wv;      // 0..4095 == b*512 + c
    const int b = row >> 9;
    const int c = row & 511;

    const float* ps = fs + ((size_t)row << 14);  // row * 16384
    const float* pt = ft + ((size_t)row << 14);
    const int*   pl = lab + ((size_t)b << 14);

    for (int it = 0; it < 64; it += 2) {
        const int i0 = (it << 8) + (lane << 2);  // float4 coalesced
        const int i1 = i0 + 256;
        const float4 vs0 = *(const float4*)(ps + i0);
        const float4 vt0 = *(const float4*)(pt + i0);
        const int4   l0  = *(const int4*)(pl + i0);
        const float4 vs1 = *(const float4*)(ps + i1);
        const float4 vt1 = *(const float4*)(pt + i1);
        const int4   l1  = *(const int4*)(pl + i1);

        // Thread-private column: non-atomic RMW is safe.
        acc[l0.x][tid] += vs0.x;
        acc[l0.y][tid] += vs0.y;
        acc[l0.z][tid] += vs0.z;
        acc[l0.w][tid] += vs0.w;
        acc[NUM_K + l0.x][tid] += vt0.x;
        acc[NUM_K + l0.y][tid] += vt0.y;
        acc[NUM_K + l0.z][tid] += vt0.z;
        acc[NUM_K + l0.w][tid] += vt0.w;

        acc[l1.x][tid] += vs1.x;
        acc[l1.y][tid] += vs1.y;
        acc[l1.z][tid] += vs1.z;
        acc[l1.w][tid] += vs1.w;
        acc[NUM_K + l1.x][tid] += vt1.x;
        acc[NUM_K + l1.y][tid] += vt1.y;
        acc[NUM_K + l1.z][tid] += vt1.z;
        acc[NUM_K + l1.w][tid] += vt1.w;
    }

    // Wave-level reduction: each thread reads only its own column, then
    // shuffle-reduce across the 64 lanes sharing this (b,c) row.
    for (int k = 0; k < NUM_K; ++k) {
        float v = acc[k][tid];
        float w = acc[NUM_K + k][tid];
#pragma unroll
        for (int off = 32; off > 0; off >>= 1) {
            v += __shfl_down(v, off, 64);
            w += __shfl_down(w, off, 64);
        }
        if (lane == 0) {
            if (mode) {  // contention-free partials [k][b][c]
                outS[(k * 8 + b) * CDIM + c] = v;
                outT[(k * 8 + b) * CDIM + c] = w;
            } else {
                atomicAdd(&outS[k * CDIM + c], v);
                atomicAdd(&outT[k * CDIM + c], w);
            }
        }
    }
}

// ---------------------------------------------------------------------------
// Kernel 2: per-class pixel counts (int atomics = native, tiny volume).
// ---------------------------------------------------------------------------
__global__ __launch_bounds__(256)
void count_kernel(const int* __restrict__ lab, int* __restrict__ counts) {
    __shared__ int h[NUM_K];
    const int tid = threadIdx.x;
    if (tid < NUM_K) h[tid] = 0;
    __syncthreads();
    const int i = blockIdx.x * 256 + tid;      // one int4 per thread
    const int4 l4 = ((const int4*)lab)[i];
    atomicAdd(&h[l4.x], 1);
    atomicAdd(&h[l4.y], 1);
    atomicAdd(&h[l4.z], 1);
    atomicAdd(&h[l4.w], 1);
    __syncthreads();
    if (tid < NUM_K) atomicAdd(&counts[tid], h[tid]);
}

// ---------------------------------------------------------------------------
// Kernel 3: reduce partials, normalize, 19x19 logits, masked LSE loss.
// ---------------------------------------------------------------------------
__global__ __launch_bounds__(1024)
void finalize_kernel(const float* __restrict__ Ss, const float* __restrict__ St,
                     const int* __restrict__ counts, float* __restrict__ out,
                     const int mode) {
    __shared__ float ms[NUM_K][CDIM];
    __shared__ float mt[NUM_K][CDIM];
    __shared__ float scs[NUM_K], sct[NUM_K], cnt[NUM_K], invd[NUM_K];
    __shared__ float logits[NUM_K][NUM_K];
    const int tid = threadIdx.x;
    if (tid < NUM_K) {
        const float cv = (float)counts[tid];
        cnt[tid] = cv;
        invd[tid] = 1.0f / fmaxf(cv, 1.0f);
    }
    __syncthreads();

    float* msf = &ms[0][0];
    float* mtf = &mt[0][0];
    for (int i = tid; i < NUM_K * CDIM; i += 1024) {
        const int k = i >> 9, c = i & 511;
        float ssum, tsum;
        if (mode) {
            ssum = 0.0f; tsum = 0.0f;
            const float* pps = Ss + (size_t)(k * 8) * CDIM + c;
            const float* ppt = St + (size_t)(k * 8) * CDIM + c;
#pragma unroll
            for (int bb = 0; bb < 8; ++bb) {
                ssum += pps[bb * CDIM];
                tsum += ppt[bb * CDIM];
            }
        } else {
            ssum = Ss[i]; tsum = St[i];
        }
        const float id = invd[k];
        msf[i] = ssum * id;
        mtf[i] = tsum * id;
    }
    __syncthreads();

    const int wv = tid >> 6, lane = tid & 63;
    // Row L2 norms -> scale factors (normalization folded into logits).
    for (int k = wv; k < NUM_K; k += 16) {
        const float4* rs = (const float4*)&ms[k][0];
        const float4* rt = (const float4*)&mt[k][0];
        const float4 a0 = rs[lane * 2], a1 = rs[lane * 2 + 1];
        const float4 b0 = rt[lane * 2], b1 = rt[lane * 2 + 1];
        float ssum = a0.x*a0.x + a0.y*a0.y + a0.z*a0.z + a0.w*a0.w
                   + a1.x*a1.x + a1.y*a1.y + a1.z*a1.z + a1.w*a1.w;
        float tsum = b0.x*b0.x + b0.y*b0.y + b0.z*b0.z + b0.w*b0.w
                   + b1.x*b1.x + b1.y*b1.y + b1.z*b1.z + b1.w*b1.w;
#pragma unroll
        for (int off = 32; off > 0; off >>= 1) {
            ssum += __shfl_down(ssum, off, 64);
            tsum += __shfl_down(tsum, off, 64);
        }
        if (lane == 0) {
            scs[k] = 1.0f / fmaxf(sqrtf(ssum), 1e-12f);
            sct[k] = 1.0f / fmaxf(sqrtf(tsum), 1e-12f);
        }
    }
    __syncthreads();

    // logits[i][j] = (norm_s[i] . norm_t[j]) / TEMP
    for (int i = wv; i < NUM_K; i += 16) {
        const float4* rs = (const float4*)&ms[i][0];
        const float4 a0 = rs[lane * 2], a1 = rs[lane * 2 + 1];
        for (int j = 0; j < NUM_K; ++j) {
            const float4* rt = (const float4*)&mt[j][0];
            const float4 b0 = rt[lane * 2], b1 = rt[lane * 2 + 1];
            float d = a0.x*b0.x + a0.y*b0.y + a0.z*b0.z + a0.w*b0.w
                    + a1.x*b1.x + a1.y*b1.y + a1.z*b1.z + a1.w*b1.w;
#pragma unroll
            for (int off = 32; off > 0; off >>= 1) d += __shfl_down(d, off, 64);
            if (lane == 0) logits[i][j] = d * scs[i] * sct[j] * 10.0f;
        }
    }
    __syncthreads();

    if (wv == 0) {
        float val = 0.0f, pres = 0.0f;
        if (lane < NUM_K) {
            float m = -3.0e38f;
            for (int j = 0; j < NUM_K; ++j) m = fmaxf(m, logits[lane][j]);
            float s = 0.0f;
            for (int j = 0; j < NUM_K; ++j) s += expf(logits[lane][j] - m);
            const float lse = m + logf(s);
            if (cnt[lane] > 0.0f) { val = logits[lane][lane] - lse; pres = 1.0f; }
        }
#pragma unroll
        for (int off = 32; off > 0; off >>= 1) {
            val += __shfl_down(val, off, 64);
            pres += __shfl_down(pres, off, 64);
        }
        if (lane == 0) out[0] = -val / pres;
    }
}

extern "C" void kernel_launch(void* const* d_in, const int* in_sizes, int n_in,
                              void* d_out, int out_size, void* d_ws, size_t ws_size,
                              hipStream_t stream) {
    const float* fs = (const float*)d_in[0];
    const float* ft = (const float*)d_in[1];
    const int* lab = (const int*)d_in[2];

    // Workspace layout: [counts: 32 ints][Ss][St]
    int* counts = (int*)d_ws;
    float* Ss = (float*)((char*)d_ws + 128);

    const size_t partial_elems = (size_t)NUM_K * 8 * CDIM;   // 77824 per tensor
    const size_t small_elems = (size_t)NUM_K * CDIM;         // 9728 per tensor
    const int mode = (ws_size >= 128 + 2 * partial_elems * sizeof(float)) ? 1 : 0;
    const size_t elems = mode ? partial_elems : small_elems;
    float* St = Ss + elems;

    // Zero counts always; zero sum buffers only in atomic fallback mode.
    const size_t zbytes = mode ? 128 : (128 + 2 * small_elems * sizeof(float));
    hipMemsetAsync(d_ws, 0, zbytes, stream);

    hipLaunchKernelGGL(count_kernel, dim3(131072 / 4 / 256), dim3(256), 0, stream,
                       lab, counts);
    hipLaunchKernelGGL(class_sum_kernel, dim3(4096 / 4), dim3(256), 0, stream,
                       fs, ft, lab, Ss, St, mode);
    hipLaunchKernelGGL(finalize_kernel, dim3(1), dim3(1024), 0, stream,
                       Ss, St, counts, (float*)d_out, mode);
}